// Round 24
// baseline (978.036 us; speedup 1.0000x reference)
//
#include <hip/hip_runtime.h>
#include <hip/hip_bf16.h>

#define NLAT 511
#define NLON 512
#define LMAX 511
#define MMAX 257
#define KT 16                 // k per tile (64 B per row segment = full line)
#define WSTR 18               // LDS row stride (16 data + 2 pad)

typedef unsigned short u16;
typedef unsigned int u32;

__device__ __forceinline__ u16 f2bf(float a) {
    __hip_bfloat16 h = __float2bfloat16(a);
    return *reinterpret_cast<u16*>(&h);
}

// A layout (f32, in d_ws): A[mi][k][j], j = c*16 + ri*8 + b.  Per-m: 65,408 B.

// ---------------------------------------------------------------------------
// Kernel 1: radix-2 LDS FFT per (ring, comp) — unchanged (verified).
// ---------------------------------------------------------------------------
__global__ __launch_bounds__(256) void fft3(const float* __restrict__ x,
                                            float* __restrict__ A,
                                            int m_lo, int m_hi) {
    const int kb   = blockIdx.x;       // 0..1021
    const int klat = kb >> 1;          // ring
    const int c    = kb & 1;           // vector component
    const int t    = threadIdx.x;

    __shared__ __align__(16) float re[8][512];
    __shared__ __align__(16) float im[8][512];

    #pragma unroll
    for (int b = 0; b < 8; ++b) {
        const float* row = x + ((size_t)(b * 2 + c) * NLAT + klat) * NLON;
        #pragma unroll
        for (int h = 0; h < 2; ++h) {
            int n  = h * 256 + t;
            int rn = (int)(__brev((u32)n) >> 23);   // 9-bit reversal
            re[b][rn] = row[n];
            im[b][rn] = 0.0f;
        }
    }
    __syncthreads();

    for (int s = 1; s <= 9; ++s) {
        const int half = 1 << (s - 1);
        const int j    = t & (half - 1);
        const int p0   = ((t >> (s - 1)) << s) + j;
        const int p1   = p0 + half;
        float sn, cs;
        sincosf(-6.28318530717958647692f * (float)j / (float)(1 << s), &sn, &cs);
        #pragma unroll
        for (int b = 0; b < 8; ++b) {
            float ar = re[b][p0], ai = im[b][p0];
            float br = re[b][p1], bi = im[b][p1];
            float tr = fmaf(br, cs, -bi * sn);
            float ti = fmaf(br, sn,  bi * cs);
            re[b][p0] = ar + tr;  im[b][p0] = ai + ti;
            re[b][p1] = ar - tr;  im[b][p1] = ai - ti;
        }
        __syncthreads();
    }

    for (int m = m_lo + t; m < m_hi; m += 256) {
        float4* d4 = (float4*)(A + ((size_t)(m - m_lo) * NLAT + klat) * 32 + c * 16);
        d4[0] = make_float4(re[0][m], re[1][m], re[2][m], re[3][m]);
        d4[1] = make_float4(re[4][m], re[5][m], re[6][m], re[7][m]);
        d4[2] = make_float4(im[0][m], im[1][m], im[2][m], im[3][m]);
        d4[3] = make_float4(im[4][m], im[5][m], im[6][m], im[7][m]);
    }
}

// ---------------------------------------------------------------------------
// Kernel 2: lane = l; A via wave-uniform SCALAR loads (SGPR operands, no LDS
// on the A path); w via double-buffered LDS tiles staged coalesced
// (16-k x 64 B row segments; T14 split: load->regs early, ds_write late,
// one barrier per tile).  Hot loop per k: 2 scalar LDS reads + 64 FMA.
// ---------------------------------------------------------------------------
__global__ __launch_bounds__(256) void leg8(const float* __restrict__ A,
                                            const float* __restrict__ w,
                                            u16* __restrict__ out,
                                            int m_lo) {
    const int mi    = blockIdx.x >> 1;
    const int m     = m_lo + mi;
    const int lhalf = blockIdx.x & 1;
    const int t     = threadIdx.x;
    const int l     = lhalf * 256 + t;
    const bool valid = (l < LMAX);
    const int L0    = lhalf * 256;

    __shared__ float wt[2][512 * WSTR];          // 2 x 36,864 B

    const float* __restrict__ Am = A + (size_t)mi * (NLAT * 32);   // uniform
    const size_t wplane = (size_t)MMAX * LMAX * NLAT;
    const float* __restrict__ wm = w + (size_t)m * LMAX * NLAT;

    float s0r[8] = {0}, s0i[8] = {0}, s1r[8] = {0}, s1i[8] = {0};
    float2 reg[16];

    // Staging map: unit u = it*256 + t; row r = u>>3 (d = r>>8, l' = r&255),
    // chunk q = u&7 (k-pair k0+2q).  8 consecutive lanes read one 64 B row
    // segment -> full-line coalescing.
#define STAGE_LOAD(K0)                                                      \
    _Pragma("unroll")                                                       \
    for (int it = 0; it < 16; ++it) {                                       \
        const int u = it * 256 + t;                                         \
        const int r = u >> 3, q = u & 7;                                    \
        const int d = r >> 8, lp = r & 255;                                 \
        int lrow = L0 + lp; if (lrow > 510) lrow = 510;                     \
        const int kk = (K0) + 2 * q;                                        \
        const size_t base = (size_t)d * wplane + (size_t)lrow * NLAT;       \
        if (kk <= 509) {                                                    \
            reg[it] = *(const float2*)(wm + base + kk);                     \
        } else {   /* kk == 510: pair (510,511); 511 invalid -> 0 */        \
            float2 v = *(const float2*)(wm + base + 509);                   \
            reg[it] = make_float2(v.y, 0.0f);                               \
        }                                                                   \
    }

#define STAGE_WRITE(BUF)                                                    \
    _Pragma("unroll")                                                       \
    for (int it = 0; it < 16; ++it) {                                       \
        const int u = it * 256 + t;                                         \
        const int r = u >> 3, q = u & 7;                                    \
        *(float2*)&wt[BUF][r * WSTR + 2 * q] = reg[it];                     \
    }

#define KSTEP(KA, wA, wB)                                                   \
    {                                                                       \
        const float* Ak = Am + (size_t)(KA) * 32;                           \
        _Pragma("unroll")                                                   \
        for (int b = 0; b < 8; ++b) {                                       \
            const float xr0 = Ak[b],      xi0 = Ak[8 + b];                  \
            const float xr1 = Ak[16 + b], xi1 = Ak[24 + b];                 \
            s0r[b] = fmaf(wA, xr0, fmaf(-wB, xi1, s0r[b]));                 \
            s0i[b] = fmaf(wA, xi0, fmaf( wB, xr1, s0i[b]));                 \
            s1r[b] = fmaf(-wB, xi0, fmaf(-wA, xr1, s1r[b]));                \
            s1i[b] = fmaf( wB, xr0, fmaf(-wA, xi1, s1i[b]));                \
        }                                                                   \
    }

    STAGE_LOAD(0)
    STAGE_WRITE(0)
    __syncthreads();

    for (int g = 0; g < 32; ++g) {
        const int cur = g & 1;
        if (g < 31) STAGE_LOAD((g + 1) * KT)          // loads fly under compute
        const int k0 = g * KT;
        #pragma unroll
        for (int kk = 0; kk < KT; ++kk) {
            const int k  = k0 + kk;
            const int kA = (k < NLAT) ? k : (NLAT - 1);   // w is 0 at k=511
            const float wA = wt[cur][t * WSTR + kk];
            const float wB = wt[cur][(256 + t) * WSTR + kk];
            KSTEP(kA, wA, wB)
        }
        if (g < 31) {
            STAGE_WRITE(cur ^ 1)                       // waits its own loads
            __syncthreads();                           // single barrier/tile
        }
    }
#undef KSTEP
#undef STAGE_WRITE
#undef STAGE_LOAD

    if (valid) {
        #pragma unroll
        for (int b = 0; b < 8; ++b) {
            const size_t c0 = ((size_t)(b * 2 + 0) * LMAX + l) * MMAX + m;
            const size_t c1 = ((size_t)(b * 2 + 1) * LMAX + l) * MMAX + m;
            // +1 SHIFT (measured R14-R17): validated flat[j] = our u16[j+1].
            out[2 * c0 + 1] = f2bf(s0r[b]);
            out[2 * c0 + 2] = f2bf(s0i[b]);
            out[2 * c1 + 1] = f2bf(s1r[b]);
            out[2 * c1 + 2] = f2bf(s1i[b]);
        }
    }
}

extern "C" void kernel_launch(void* const* d_in, const int* in_sizes, int n_in,
                              void* d_out, int out_size, void* d_ws, size_t ws_size,
                              hipStream_t stream) {
    const float* x = (const float*)d_in[0];   // [8][2][511][512] f32
    const float* w = (const float*)d_in[1];   // [2][257][511][511] f32
    u16* out = (u16*)d_out;                   // bf16, validated at +2 B
    float* A = (float*)d_ws;

    const size_t per_m = (size_t)NLAT * 32 * sizeof(float);   // 65,408 B
    int mchunk = (int)(ws_size / per_m);
    if (mchunk > MMAX) mchunk = MMAX;
    if (mchunk < 1) mchunk = 1;

    for (int m0 = 0; m0 < MMAX; m0 += mchunk) {
        int m1 = m0 + mchunk;
        if (m1 > MMAX) m1 = MMAX;
        const int mc = m1 - m0;
        fft3<<<NLAT * 2, 256, 0, stream>>>(x, A, m0, m1);
        leg8<<<mc * 2, 256, 0, stream>>>(A, w, out, m0);
    }
}

// Round 25
// 528.406 us; speedup vs baseline: 1.8509x; 1.8509x over previous
//
#include <hip/hip_runtime.h>
#include <hip/hip_bf16.h>

#define NLAT 511
#define NLON 512
#define LMAX 511
#define MMAX 257
#define PAD 34              // A row stride in LDS floats: b64-aligned, 2-way banks

typedef unsigned short u16;
typedef unsigned int u32;

__device__ __forceinline__ u16 f2bf(float a) {
    __hip_bfloat16 h = __float2bfloat16(a);
    return *reinterpret_cast<u16*>(&h);
}

// A layout (f32, in d_ws): A[mi][k][j], j = c*16 + ri*8 + b.  Per-m: 65,408 B.

// ---------------------------------------------------------------------------
// Kernel 1: radix-2 LDS FFT per (ring, comp) — unchanged (verified).
// ---------------------------------------------------------------------------
__global__ __launch_bounds__(256) void fft3(const float* __restrict__ x,
                                            float* __restrict__ A,
                                            int m_lo, int m_hi) {
    const int kb   = blockIdx.x;       // 0..1021
    const int klat = kb >> 1;          // ring
    const int c    = kb & 1;           // vector component
    const int t    = threadIdx.x;

    __shared__ __align__(16) float re[8][512];
    __shared__ __align__(16) float im[8][512];

    #pragma unroll
    for (int b = 0; b < 8; ++b) {
        const float* row = x + ((size_t)(b * 2 + c) * NLAT + klat) * NLON;
        #pragma unroll
        for (int h = 0; h < 2; ++h) {
            int n  = h * 256 + t;
            int rn = (int)(__brev((u32)n) >> 23);   // 9-bit reversal
            re[b][rn] = row[n];
            im[b][rn] = 0.0f;
        }
    }
    __syncthreads();

    for (int s = 1; s <= 9; ++s) {
        const int half = 1 << (s - 1);
        const int j    = t & (half - 1);
        const int p0   = ((t >> (s - 1)) << s) + j;
        const int p1   = p0 + half;
        float sn, cs;
        sincosf(-6.28318530717958647692f * (float)j / (float)(1 << s), &sn, &cs);
        #pragma unroll
        for (int b = 0; b < 8; ++b) {
            float ar = re[b][p0], ai = im[b][p0];
            float br = re[b][p1], bi = im[b][p1];
            float tr = fmaf(br, cs, -bi * sn);
            float ti = fmaf(br, sn,  bi * cs);
            re[b][p0] = ar + tr;  im[b][p0] = ai + ti;
            re[b][p1] = ar - tr;  im[b][p1] = ai - ti;
        }
        __syncthreads();
    }

    for (int m = m_lo + t; m < m_hi; m += 256) {
        float4* d4 = (float4*)(A + ((size_t)(m - m_lo) * NLAT + klat) * 32 + c * 16);
        d4[0] = make_float4(re[0][m], re[1][m], re[2][m], re[3][m]);
        d4[1] = make_float4(re[4][m], re[5][m], re[6][m], re[7][m]);
        d4[2] = make_float4(im[0][m], im[1][m], im[2][m], im[3][m]);
        d4[3] = make_float4(im[4][m], im[5][m], im[6][m], im[7][m]);
    }
}

// ---------------------------------------------------------------------------
// Kernel 2: leg9 — R23's lane=k structure with the register budget fixed:
// wave owns 2 l (acc[2][32] = 64 VGPR; no spill).  Block = (mi, l-group of
// 8); lanes cover 64 consecutive k per tile -> w loads coalesced 256 B.
// A[m] in LDS [k][34]; per-l reduce via in-LDS transpose + shfl_xor(32).
// ---------------------------------------------------------------------------
__global__ __launch_bounds__(256, 2) void leg9(const float* __restrict__ A,
                                               const float* __restrict__ w,
                                               u16* __restrict__ out,
                                               int m_lo) {
    const int lg   = blockIdx.x & 63;          // l-group 0..63 (8 l each)
    const int mi   = blockIdx.x >> 6;
    const int m    = m_lo + mi;
    const int t    = threadIdx.x;
    const int wid  = t >> 6;                   // wave 0..3
    const int lane = t & 63;

    __shared__ float As[NLAT * PAD];           // 69,496 B -> 2 blocks/CU

    // stage A[mi] -> LDS (coalesced float2)
    {
        const float2* src = (const float2*)(A + (size_t)mi * (NLAT * 32));
        for (int i = t; i < NLAT * 16; i += 256) {
            const int k = i >> 4, p = i & 15;
            *(float2*)&As[k * PAD + 2 * p] = src[i];
        }
    }
    __syncthreads();

    // this wave's 2 l rows
    const int l0 = lg * 8 + wid * 2;
    const float* w0r[2];
    const float* w1r[2];
    #pragma unroll
    for (int li = 0; li < 2; ++li) {
        const int l  = l0 + li;
        const int lc = (l < LMAX) ? l : (LMAX - 1);
        w0r[li] = w + ((size_t)m * LMAX + lc) * NLAT;
        w1r[li] = w0r[li] + (size_t)MMAX * LMAX * NLAT;
    }

    float acc0[32], acc1[32];
    #pragma unroll
    for (int j = 0; j < 32; ++j) { acc0[j] = 0.0f; acc1[j] = 0.0f; }

    for (int tile = 0; tile < 8; ++tile) {
        const int myk = tile * 64 + lane;
        const bool vk = (myk < NLAT);
        const int kc  = vk ? myk : (NLAT - 1);

        float wa0, wb0, wa1, wb1;
        {   // coalesced 256 B wave loads (lane = consecutive k)
            const float va0 = w0r[0][kc], vb0 = w1r[0][kc];
            const float va1 = w0r[1][kc], vb1 = w1r[1][kc];
            wa0 = vk ? va0 : 0.0f;  wb0 = vk ? vb0 : 0.0f;
            wa1 = vk ? va1 : 0.0f;  wb1 = vk ? vb1 : 0.0f;
        }

        float Ak[32];
        {
            const float* base = &As[kc * PAD];
            #pragma unroll
            for (int p = 0; p < 16; ++p) {     // 16 x ds_read_b64, 2-way banks
                const float2 v = *(const float2*)&base[2 * p];
                Ak[2 * p]     = v.x;
                Ak[2 * p + 1] = v.y;
            }
        }

        #pragma unroll
        for (int b = 0; b < 8; ++b) {
            acc0[b]      = fmaf(wa0, Ak[b],      fmaf(-wb0, Ak[24 + b], acc0[b]));
            acc0[8 + b]  = fmaf(wa0, Ak[8 + b],  fmaf( wb0, Ak[16 + b], acc0[8 + b]));
            acc0[16 + b] = fmaf(-wb0, Ak[8 + b], fmaf(-wa0, Ak[16 + b], acc0[16 + b]));
            acc0[24 + b] = fmaf(wb0, Ak[b],      fmaf(-wa0, Ak[24 + b], acc0[24 + b]));
            acc1[b]      = fmaf(wa1, Ak[b],      fmaf(-wb1, Ak[24 + b], acc1[b]));
            acc1[8 + b]  = fmaf(wa1, Ak[8 + b],  fmaf( wb1, Ak[16 + b], acc1[8 + b]));
            acc1[16 + b] = fmaf(-wb1, Ak[8 + b], fmaf(-wa1, Ak[16 + b], acc1[16 + b]));
            acc1[24 + b] = fmaf(wb1, Ak[b],      fmaf(-wa1, Ak[24 + b], acc1[24 + b]));
        }
    }

    // ---- per-l reduce across 64 lanes via LDS transpose (reuse As) ----
    float* red = As + wid * (64 * PAD);        // 8,704 B per wave
    const int o = lane & 31;
    const int h = lane >> 5;

    #pragma unroll
    for (int li = 0; li < 2; ++li) {
        __syncthreads();                       // k-loop done / prev reads done
        const float* a = li ? acc1 : acc0;
        #pragma unroll
        for (int p = 0; p < 16; ++p)
            *(float2*)&red[lane * PAD + 2 * p] = make_float2(a[2 * p], a[2 * p + 1]);
        __syncthreads();                       // writes visible
        float s = 0.0f;
        #pragma unroll
        for (int i = 0; i < 32; ++i)           // banks (2i+o)%32, h: 2-way free
            s += red[(32 * h + i) * PAD + o];
        s += __shfl_xor(s, 32, 64);
        const int l = l0 + li;
        if (lane < 32 && l < LMAX) {
            const int cout = o >> 4, ri = (o >> 3) & 1, b = o & 7;
            const size_t cidx = ((size_t)(b * 2 + cout) * LMAX + l) * MMAX + m;
            // +1 SHIFT (measured R14-R17): validated flat[j] = our u16[j+1].
            out[2 * cidx + 1 + ri] = f2bf(s);
        }
    }
}

extern "C" void kernel_launch(void* const* d_in, const int* in_sizes, int n_in,
                              void* d_out, int out_size, void* d_ws, size_t ws_size,
                              hipStream_t stream) {
    const float* x = (const float*)d_in[0];   // [8][2][511][512] f32
    const float* w = (const float*)d_in[1];   // [2][257][511][511] f32
    u16* out = (u16*)d_out;                   // bf16, validated at +2 B
    float* A = (float*)d_ws;

    const size_t per_m = (size_t)NLAT * 32 * sizeof(float);   // 65,408 B
    int mchunk = (int)(ws_size / per_m);
    if (mchunk > MMAX) mchunk = MMAX;
    if (mchunk < 1) mchunk = 1;

    for (int m0 = 0; m0 < MMAX; m0 += mchunk) {
        int m1 = m0 + mchunk;
        if (m1 > MMAX) m1 = MMAX;
        const int mc = m1 - m0;
        fft3<<<NLAT * 2, 256, 0, stream>>>(x, A, m0, m1);
        leg9<<<mc * 64, 256, 0, stream>>>(A, w, out, m0);
    }
}

// Round 26
// 377.744 us; speedup vs baseline: 2.5891x; 1.3988x over previous
//
#include <hip/hip_runtime.h>
#include <hip/hip_bf16.h>

#define NLAT 511
#define NLON 512
#define LMAX 511
#define MMAX 257
#define PAD 34              // A row stride in LDS floats: b64-aligned, 2-way banks

typedef unsigned short u16;
typedef unsigned int u32;

__device__ __forceinline__ u16 f2bf(float a) {
    __hip_bfloat16 h = __float2bfloat16(a);
    return *reinterpret_cast<u16*>(&h);
}

// A layout (f32, in d_ws): A[mi][k][j], j = c*16 + ri*8 + b.  Per-m: 65,408 B.

// ---------------------------------------------------------------------------
// Kernel 1: radix-2 LDS FFT per (ring, comp) — unchanged (verified).
// ---------------------------------------------------------------------------
__global__ __launch_bounds__(256) void fft3(const float* __restrict__ x,
                                            float* __restrict__ A,
                                            int m_lo, int m_hi) {
    const int kb   = blockIdx.x;       // 0..1021
    const int klat = kb >> 1;          // ring
    const int c    = kb & 1;           // vector component
    const int t    = threadIdx.x;

    __shared__ __align__(16) float re[8][512];
    __shared__ __align__(16) float im[8][512];

    #pragma unroll
    for (int b = 0; b < 8; ++b) {
        const float* row = x + ((size_t)(b * 2 + c) * NLAT + klat) * NLON;
        #pragma unroll
        for (int h = 0; h < 2; ++h) {
            int n  = h * 256 + t;
            int rn = (int)(__brev((u32)n) >> 23);   // 9-bit reversal
            re[b][rn] = row[n];
            im[b][rn] = 0.0f;
        }
    }
    __syncthreads();

    for (int s = 1; s <= 9; ++s) {
        const int half = 1 << (s - 1);
        const int j    = t & (half - 1);
        const int p0   = ((t >> (s - 1)) << s) + j;
        const int p1   = p0 + half;
        float sn, cs;
        sincosf(-6.28318530717958647692f * (float)j / (float)(1 << s), &sn, &cs);
        #pragma unroll
        for (int b = 0; b < 8; ++b) {
            float ar = re[b][p0], ai = im[b][p0];
            float br = re[b][p1], bi = im[b][p1];
            float tr = fmaf(br, cs, -bi * sn);
            float ti = fmaf(br, sn,  bi * cs);
            re[b][p0] = ar + tr;  im[b][p0] = ai + ti;
            re[b][p1] = ar - tr;  im[b][p1] = ai - ti;
        }
        __syncthreads();
    }

    for (int m = m_lo + t; m < m_hi; m += 256) {
        float4* d4 = (float4*)(A + ((size_t)(m - m_lo) * NLAT + klat) * 32 + c * 16);
        d4[0] = make_float4(re[0][m], re[1][m], re[2][m], re[3][m]);
        d4[1] = make_float4(re[4][m], re[5][m], re[6][m], re[7][m]);
        d4[2] = make_float4(im[0][m], im[1][m], im[2][m], im[3][m]);
        d4[3] = make_float4(im[4][m], im[5][m], im[6][m], im[7][m]);
    }
}

// ---------------------------------------------------------------------------
// Kernel 2: leg10 — lane = k, 4 l per wave, NAMED accumulator arrays
// (acc0..acc3: all indices compile-time -> no scratch; ~190 VGPR target,
// launch_bounds(256,2) allows 256).  Everything else = proven leg9 path:
// coalesced 256 B w loads, A in LDS [k][34] (0 conflicts measured),
// in-LDS transpose reduce + shfl_xor(32), +1-shifted bf16 store.
// ---------------------------------------------------------------------------
__global__ __launch_bounds__(256, 2) void leg10(const float* __restrict__ A,
                                                const float* __restrict__ w,
                                                u16* __restrict__ out,
                                                int m_lo) {
    const int lg   = blockIdx.x & 31;          // l-group 0..31 (16 l each)
    const int mi   = blockIdx.x >> 5;
    const int m    = m_lo + mi;
    const int t    = threadIdx.x;
    const int wid  = t >> 6;                   // wave 0..3
    const int lane = t & 63;

    __shared__ float As[NLAT * PAD];           // 69,496 B -> 2 blocks/CU

    // stage A[mi] -> LDS (coalesced float2)
    {
        const float2* src = (const float2*)(A + (size_t)mi * (NLAT * 32));
        for (int i = t; i < NLAT * 16; i += 256) {
            const int k = i >> 4, p = i & 15;
            *(float2*)&As[k * PAD + 2 * p] = src[i];
        }
    }
    __syncthreads();

    // this wave's 4 l rows
    const int l0 = lg * 16 + wid * 4;
    const float* w0r[4];
    const float* w1r[4];
    #pragma unroll
    for (int li = 0; li < 4; ++li) {
        const int l  = l0 + li;
        const int lc = (l < LMAX) ? l : (LMAX - 1);
        w0r[li] = w + ((size_t)m * LMAX + lc) * NLAT;
        w1r[li] = w0r[li] + (size_t)MMAX * LMAX * NLAT;
    }

    float acc0[32], acc1[32], acc2[32], acc3[32];
    #pragma unroll
    for (int j = 0; j < 32; ++j) { acc0[j] = 0.f; acc1[j] = 0.f; acc2[j] = 0.f; acc3[j] = 0.f; }

    for (int tile = 0; tile < 8; ++tile) {
        const int myk = tile * 64 + lane;
        const bool vk = (myk < NLAT);
        const int kc  = vk ? myk : (NLAT - 1);

        float wa0, wb0, wa1, wb1, wa2, wb2, wa3, wb3;
        {   // coalesced 256 B wave loads (lane = consecutive k)
            const float v0 = w0r[0][kc], g0 = w1r[0][kc];
            const float v1 = w0r[1][kc], g1 = w1r[1][kc];
            const float v2 = w0r[2][kc], g2 = w1r[2][kc];
            const float v3 = w0r[3][kc], g3 = w1r[3][kc];
            wa0 = vk ? v0 : 0.f;  wb0 = vk ? g0 : 0.f;
            wa1 = vk ? v1 : 0.f;  wb1 = vk ? g1 : 0.f;
            wa2 = vk ? v2 : 0.f;  wb2 = vk ? g2 : 0.f;
            wa3 = vk ? v3 : 0.f;  wb3 = vk ? g3 : 0.f;
        }

        float Ak[32];
        {
            const float* base = &As[kc * PAD];
            #pragma unroll
            for (int p = 0; p < 16; ++p) {     // 16 x ds_read_b64, 2-way banks
                const float2 v = *(const float2*)&base[2 * p];
                Ak[2 * p]     = v.x;
                Ak[2 * p + 1] = v.y;
            }
        }

#define ACCUM(ACC, WA, WB)                                                  \
        _Pragma("unroll")                                                   \
        for (int b = 0; b < 8; ++b) {                                       \
            ACC[b]      = fmaf(WA, Ak[b],      fmaf(-WB, Ak[24 + b], ACC[b]));      \
            ACC[8 + b]  = fmaf(WA, Ak[8 + b],  fmaf( WB, Ak[16 + b], ACC[8 + b]));  \
            ACC[16 + b] = fmaf(-WB, Ak[8 + b], fmaf(-WA, Ak[16 + b], ACC[16 + b])); \
            ACC[24 + b] = fmaf(WB, Ak[b],      fmaf(-WA, Ak[24 + b], ACC[24 + b])); \
        }
        ACCUM(acc0, wa0, wb0)
        ACCUM(acc1, wa1, wb1)
        ACCUM(acc2, wa2, wb2)
        ACCUM(acc3, wa3, wb3)
#undef ACCUM
    }

    // ---- per-l reduce across 64 lanes via LDS transpose (reuse As) ----
    float* red = As + wid * (64 * PAD);        // 8,704 B per wave
    const int o = lane & 31;
    const int h = lane >> 5;

    #pragma unroll
    for (int li = 0; li < 4; ++li) {
        __syncthreads();                       // k-loop done / prev reads done
        const float* a = (li == 0) ? acc0 : (li == 1) ? acc1
                       : (li == 2) ? acc2 : acc3;
        #pragma unroll
        for (int p = 0; p < 16; ++p)
            *(float2*)&red[lane * PAD + 2 * p] = make_float2(a[2 * p], a[2 * p + 1]);
        __syncthreads();                       // writes visible
        float s = 0.0f;
        #pragma unroll
        for (int i = 0; i < 32; ++i)           // banks (2i+o)%32, 2-way free
            s += red[(32 * h + i) * PAD + o];
        s += __shfl_xor(s, 32, 64);
        const int l = l0 + li;
        if (lane < 32 && l < LMAX) {
            const int cout = o >> 4, ri = (o >> 3) & 1, b = o & 7;
            const size_t cidx = ((size_t)(b * 2 + cout) * LMAX + l) * MMAX + m;
            // +1 SHIFT (measured R14-R17): validated flat[j] = our u16[j+1].
            out[2 * cidx + 1 + ri] = f2bf(s);
        }
    }
}

extern "C" void kernel_launch(void* const* d_in, const int* in_sizes, int n_in,
                              void* d_out, int out_size, void* d_ws, size_t ws_size,
                              hipStream_t stream) {
    const float* x = (const float*)d_in[0];   // [8][2][511][512] f32
    const float* w = (const float*)d_in[1];   // [2][257][511][511] f32
    u16* out = (u16*)d_out;                   // bf16, validated at +2 B
    float* A = (float*)d_ws;

    const size_t per_m = (size_t)NLAT * 32 * sizeof(float);   // 65,408 B
    int mchunk = (int)(ws_size / per_m);
    if (mchunk > MMAX) mchunk = MMAX;
    if (mchunk < 1) mchunk = 1;

    for (int m0 = 0; m0 < MMAX; m0 += mchunk) {
        int m1 = m0 + mchunk;
        if (m1 > MMAX) m1 = MMAX;
        const int mc = m1 - m0;
        fft3<<<NLAT * 2, 256, 0, stream>>>(x, A, m0, m1);
        leg10<<<mc * 32, 256, 0, stream>>>(A, w, out, m0);
    }
}